// Round 11
// baseline (255.049 us; speedup 1.0000x reference)
//
#include <hip/hip_runtime.h>
#include <hip/hip_bf16.h>
#include <hip/hip_fp16.h>

// Problem constants (match reference)
#define NN    100000
#define EE    1600000
#define ETOT  1700000   // EE + NN self loops
#define IN_D  128
#define C1    256       // H*HID
#define NHEAD 4
#define HID   64
#define OUTD  2
#define SLOPE 0.2f
#define SLOTS 64        // padded CSR row capacity; deg = 1+Poisson(16), P(>=64) ~ 1e-12
#define BB    8         // edges per thread in bucket pass
#define NBKT  196       // ceil(NN/512) dst buckets of 512 nodes
#define BCAP  12288     // bucket capacity (mean 8674, sd ~93)

#define BKT_BLOCKS  ((ETOT + 256 * BB - 1) / (256 * BB))   // 831
#define CSR_BLOCKS  (2 * NBKT)                              // 392 (parity split)
#define GEMM_BLOCKS (NN / 16)                               // 6250

typedef _Float16 f16x8 __attribute__((ext_vector_type(8)));
typedef float f32x4 __attribute__((ext_vector_type(4)));

__device__ __forceinline__ float lrelu(float x) {
    return x > 0.0f ? x : SLOPE * x;
}

struct alignas(8) h4 { __half2 a, b; };

// ---------- kernel 0: W1 [128][256] f32 -> W1T [256][128] fp16 ----------
__global__ __launch_bounds__(256) void convert_w1(
    const float* __restrict__ W1, _Float16* __restrict__ W1T)
{
    int idx = blockIdx.x * 256 + threadIdx.x;
    int k = idx >> 8;
    int c = idx & 255;
    W1T[c * IN_D + k] = (_Float16)W1[idx];
}

// ---------- kernel 1: bucket binning (latency-bound) ∥ MFMA gemm1 (BW-bound) ----------
// Independent work co-scheduled: gemm fills bucket's scatter-latency stalls.
__global__ __launch_bounds__(256) void bucket_and_gemm(
    const int* __restrict__ ei, int* __restrict__ gcnt, int* __restrict__ buf,
    const float* __restrict__ x, const _Float16* __restrict__ W1T,
    const float* __restrict__ a1s, const float* __restrict__ a1d,
    __half* __restrict__ hh1, float* __restrict__ s1s, float* __restrict__ s1d)
{
    __shared__ int hist[NBKT], curb[NBKT], gbase[NBKT];
    __shared__ _Float16 xl[16][136];

    if (blockIdx.x < BKT_BLOCKS) {
        const int t = threadIdx.x;
        for (int i = t; i < NBKT; i += 256) { hist[i] = 0; curb[i] = 0; }
        __syncthreads();

        const int base = blockIdx.x * 256 * BB;
        int srcs[BB], dsts[BB];
#pragma unroll
        for (int i = 0; i < BB; i++) {
            const int e = base + i * 256 + t;
            int s = -1, d = -1;
            if (e < ETOT) {
                if (e < EE) { s = ei[e]; d = ei[EE + e]; }
                else        { s = d = e - EE; }
            }
            srcs[i] = s; dsts[i] = d;
            if (d >= 0) atomicAdd(&hist[d >> 9], 1);
        }
        __syncthreads();
        for (int i = t; i < NBKT; i += 256)
            if (hist[i] > 0) gbase[i] = atomicAdd(&gcnt[i], hist[i]);
        __syncthreads();
#pragma unroll
        for (int i = 0; i < BB; i++) {
            if (dsts[i] >= 0) {
                int b = dsts[i] >> 9;
                int slot = atomicAdd(&curb[b], 1);
                int pos = gbase[b] + slot;
                // pack: local-dst (9b) << 17 | src (17b; NN < 131072)
                if (pos < BCAP) buf[b * BCAP + pos] = ((dsts[i] & 511) << 17) | srcs[i];
            }
        }
        return;
    }

    // ---- gemm path: h1 = x @ W1 via MFMA, fused s1 scores ----
    const int tid = threadIdx.x;
    const int n0 = (blockIdx.x - BKT_BLOCKS) * 16;
    {
        const int row = tid >> 4;
        const int col = (tid & 15) * 8;
        const float4* xs = (const float4*)(x + (long)(n0 + row) * IN_D + col);
        float4 v0 = xs[0], v1 = xs[1];
        f16x8 hv;
        hv[0] = (_Float16)v0.x; hv[1] = (_Float16)v0.y;
        hv[2] = (_Float16)v0.z; hv[3] = (_Float16)v0.w;
        hv[4] = (_Float16)v1.x; hv[5] = (_Float16)v1.y;
        hv[6] = (_Float16)v1.z; hv[7] = (_Float16)v1.w;
        *(f16x8*)&xl[row][col] = hv;
    }
    __syncthreads();

    const int lane = tid & 63;
    const int w = tid >> 6;                     // wave = head
    const int nd = lane & 15;                   // node within tile
    const int g = lane >> 4;                    // k-group / channel-group

    f16x8 bfrag[4];
#pragma unroll
    for (int ks = 0; ks < 4; ks++)
        bfrag[ks] = *(const f16x8*)&xl[nd][ks * 32 + g * 8];

    f32x4 acc[4] = {{0.f,0.f,0.f,0.f},{0.f,0.f,0.f,0.f},
                    {0.f,0.f,0.f,0.f},{0.f,0.f,0.f,0.f}};
#pragma unroll
    for (int t = 0; t < 4; t++) {
        const _Float16* wbase = W1T + (64 * w + 16 * t + nd) * IN_D + g * 8;
#pragma unroll
        for (int ks = 0; ks < 4; ks++) {
            f16x8 afrag = *(const f16x8*)(wbase + ks * 32);
            acc[t] = __builtin_amdgcn_mfma_f32_16x16x32_f16(
                afrag, bfrag[ks], acc[t], 0, 0, 0);
        }
    }

    float vs = 0.f, vd = 0.f;
#pragma unroll
    for (int t = 0; t < 4; t++) {
        const int cbase = 64 * w + 16 * t + 4 * g;
        const float4 as4 = *(const float4*)(a1s + cbase);
        const float4 ad4 = *(const float4*)(a1d + cbase);
        vs += acc[t][0] * as4.x + acc[t][1] * as4.y
            + acc[t][2] * as4.z + acc[t][3] * as4.w;
        vd += acc[t][0] * ad4.x + acc[t][1] * ad4.y
            + acc[t][2] * ad4.z + acc[t][3] * ad4.w;
        h4 hv;
        hv.a = __floats2half2_rn(acc[t][0], acc[t][1]);
        hv.b = __floats2half2_rn(acc[t][2], acc[t][3]);
        *(h4*)&hh1[(long)(n0 + nd) * C1 + cbase] = hv;
    }
    vs += __shfl_xor(vs, 16); vs += __shfl_xor(vs, 32);
    vd += __shfl_xor(vd, 16); vd += __shfl_xor(vd, 32);
    if (lane < 16) {
        s1s[(n0 + lane) * NHEAD + w] = vs;
        s1d[(n0 + lane) * NHEAD + w] = vd;
    }
}

// ---------- kernel 2: per-bucket CSR placement (parity-split, LDS counters) ----------
__global__ __launch_bounds__(256) void csr_place(
    const int* __restrict__ gcnt, const int* __restrict__ buf,
    int* __restrict__ deg, int* __restrict__ csr)
{
    __shared__ int cur[256];
    const int t = threadIdx.x;
    const int b = blockIdx.x >> 1;
    const int par = blockIdx.x & 1;
    cur[t] = 0;
    __syncthreads();
    const int cnt = min(gcnt[b], BCAP);
    const int* bp = buf + b * BCAP;
    const int n0 = b * 512;
    for (int i = t; i < cnt; i += 256) {
        int v = bp[i];
        int dl = v >> 17;
        if ((dl & 1) == par) {
            int slot = atomicAdd(&cur[dl >> 1], 1);
            if (slot < SLOTS) csr[(n0 + dl) * SLOTS + slot] = v & 0x1FFFF;
        }
    }
    __syncthreads();
    const int n = n0 + 2 * t + par;              // node for counter t
    if (n < NN) deg[n] = min(cur[t], SLOTS);
}

// ---------- fused layer-1: wave per dst, uniform masked 16-edge chunks ----------
__global__ __launch_bounds__(256) void l1_fused(
    const int* __restrict__ csr, const int* __restrict__ deg,
    const float* __restrict__ s1s, const float* __restrict__ s1d,
    const __half* __restrict__ hh1, const float* __restrict__ b1,
    const float* __restrict__ W2, const float* __restrict__ a2s,
    const float* __restrict__ a2d, float4* __restrict__ nrec)
{
    const int lane = threadIdx.x & 63;
    const int wid = threadIdx.x >> 6;
    const int n = blockIdx.x * 4 + wid;
    if (n >= NN) return;

    const int eid = lane & 15;
    const int h = lane >> 4;
    const int hsel = lane & 48;
    const int dn = deg[n];                      // pre-clamped <= SLOTS, >= 1
    const int st = n * SLOTS;
    const h4* __restrict__ hb = (const h4*)hh1; // h4-unit base (row = 64 h4)

    const float4 sdv = ((const float4*)s1d)[n];
    const float sdh = (h == 0) ? sdv.x : (h == 1) ? sdv.y
                    : (h == 2) ? sdv.z : sdv.w;

    float a0 = 0.f, a1 = 0.f, a2 = 0.f, a3 = 0.f, dl = 0.f;

    const int nch = (dn + 15) >> 4;
    for (int c = 0; c < nch; ++c) {
        const int idx = c * 16 + eid;
        const int eidx = idx < dn ? idx : dn - 1;     // clamp to valid slot
        int sc = csr[st + eidx];
        float ssh = s1s[sc * 4 + h];                  // scalar gather, own head
        float w = (idx < dn) ? __expf(lrelu(ssh + sdh)) : 0.f;
#pragma unroll
        for (int j = 0; j < 16; ++j) {
            int sj = __builtin_amdgcn_readlane(sc, j);
            float wv = __shfl(w, hsel | j);           // 0 for masked edges
            h4 hv = hb[(sj << 6) + lane];             // 32-bit row indexing
            float2 f01 = __half22float2(hv.a);
            float2 f23 = __half22float2(hv.b);
            dl += wv;
            a0 = fmaf(wv, f01.x, a0);
            a1 = fmaf(wv, f01.y, a1);
            a2 = fmaf(wv, f23.x, a2);
            a3 = fmaf(wv, f23.y, a3);
        }
    }

    const float4 bv = ((const float4*)b1)[lane];
    float v0 = a0 / dl + bv.x;
    float v1 = a1 / dl + bv.y;
    float v2 = a2 / dl + bv.z;
    float v3 = a3 / dl + bv.w;
    v0 = v0 > 0.f ? v0 : expm1f(v0);
    v1 = v1 > 0.f ? v1 : expm1f(v1);
    v2 = v2 > 0.f ? v2 : expm1f(v2);
    v3 = v3 > 0.f ? v3 : expm1f(v3);

    const float4 wa = ((const float4*)W2)[lane * 2];
    const float4 wb = ((const float4*)W2)[lane * 2 + 1];
    float p0 = v0 * wa.x + v1 * wa.z + v2 * wb.x + v3 * wb.z;
    float p1 = v0 * wa.y + v1 * wa.w + v2 * wb.y + v3 * wb.w;
#pragma unroll
    for (int off = 32; off >= 1; off >>= 1) {
        p0 += __shfl_xor(p0, off);
        p1 += __shfl_xor(p1, off);
    }
    if (lane == 0) {
        nrec[n] = make_float4(p0, p1,
                              p0 * a2s[0] + p1 * a2s[1],
                              p0 * a2d[0] + p1 * a2d[1]);
    }
}

// ---------- fused layer-2: 16 lanes per dst, single 16B gather per edge ----------
__global__ __launch_bounds__(256) void l2_fused(
    const int* __restrict__ csr, const int* __restrict__ deg,
    const float4* __restrict__ nrec, const float* __restrict__ b2,
    float* __restrict__ out)
{
    const int sl = threadIdx.x & 15;
    const int grp = threadIdx.x >> 4;
    const int n = blockIdx.x * 16 + grp;
    if (n >= NN) return;

    const int dn = deg[n];
    const float sd = nrec[n].w;
    float den = 0.f, a0 = 0.f, a1 = 0.f;
    for (int slot = sl; slot < dn; slot += 16) {
        int s = csr[n * SLOTS + slot];
        float4 r = nrec[s];
        float w = __expf(lrelu(r.z + sd));
        den += w;
        a0 = fmaf(w, r.x, a0);
        a1 = fmaf(w, r.y, a1);
    }
#pragma unroll
    for (int off = 8; off >= 1; off >>= 1) {
        den += __shfl_xor(den, off);
        a0  += __shfl_xor(a0, off);
        a1  += __shfl_xor(a1, off);
    }
    if (sl == 0) {
        out[n * 2]     = a0 / den + b2[0];
        out[n * 2 + 1] = a1 / den + b2[1];
    }
}

extern "C" void kernel_launch(void* const* d_in, const int* in_sizes, int n_in,
                              void* d_out, int out_size, void* d_ws, size_t ws_size,
                              hipStream_t stream) {
    const float* x   = (const float*)d_in[0];
    const int*   ei  = (const int*)d_in[1];
    const float* W1  = (const float*)d_in[2];
    const float* a1s = (const float*)d_in[3];
    const float* a1d = (const float*)d_in[4];
    const float* b1  = (const float*)d_in[5];
    const float* W2  = (const float*)d_in[6];
    const float* a2s = (const float*)d_in[7];
    const float* a2d = (const float*)d_in[8];
    const float* b2  = (const float*)d_in[9];
    float* out = (float*)d_out;

    // workspace layout (all segments 16B-aligned)
    float* ws = (float*)d_ws;
    __half* hh1 = (__half*)ws;                   // NN*C1 halves = 51.2 MB
    float* s1s = ws + (long)NN * C1 / 2;         // NN*4 floats
    float* s1d = s1s + NN * NHEAD;               // NN*4 floats
    float4* nrec = (float4*)(s1d + NN * NHEAD);  // NN float4 = 1.6 MB
    int* deg  = (int*)(nrec + NN);               // NN
    int* csr  = deg + NN;                        // NN*SLOTS = 25.6 MB
    _Float16* W1T = (_Float16*)(csr + (long)NN * SLOTS); // 64 KB
    int* gcnt = (int*)(W1T + C1 * IN_D);         // 256 ints (memset region)
    int* buf = gcnt + 256;                       // NBKT*BCAP ints = 9.6 MB

    hipMemsetAsync(gcnt, 0, 256 * sizeof(int), stream);

    convert_w1<<<128, 256, 0, stream>>>(W1, W1T);
    bucket_and_gemm<<<BKT_BLOCKS + GEMM_BLOCKS, 256, 0, stream>>>(
        ei, gcnt, buf, x, W1T, a1s, a1d, hh1, s1s, s1d);
    csr_place<<<CSR_BLOCKS, 256, 0, stream>>>(gcnt, buf, deg, csr);
    l1_fused<<<(NN + 3) / 4, 256, 0, stream>>>(csr, deg, s1s, s1d, hh1,
                                               b1, W2, a2s, a2d, nrec);
    l2_fused<<<(NN + 15) / 16, 256, 0, stream>>>(csr, deg, nrec, b2, out);
}

// Round 12
// 226.117 us; speedup vs baseline: 1.1280x; 1.1280x over previous
//
#include <hip/hip_runtime.h>
#include <hip/hip_bf16.h>
#include <hip/hip_fp16.h>

// Problem constants (match reference)
#define NN    100000
#define EE    1600000
#define ETOT  1700000   // EE + NN self loops
#define IN_D  128
#define C1    256       // H*HID
#define NHEAD 4
#define HID   64
#define OUTD  2
#define SLOPE 0.2f
#define SLOTS 64        // padded CSR row capacity; deg = 1+Poisson(16), P(>=64) ~ 1e-12
#define BB    16        // edges per thread in bucket pass
#define NBKT  196       // ceil(NN/512) dst buckets of 512 nodes
#define BCAP  12288     // bucket capacity (mean 8674, sd ~93)

#define BKT_BLOCKS  ((ETOT + 256 * BB - 1) / (256 * BB))   // 416
#define CONV_BLOCKS 128
#define CSR_BLOCKS  (2 * NBKT)                              // 392 (parity split)
#define GEMM_BLOCKS (NN / 32)                               // 3125

typedef _Float16 f16x8 __attribute__((ext_vector_type(8)));
typedef float f32x4 __attribute__((ext_vector_type(4)));

__device__ __forceinline__ float lrelu(float x) {
    return x > 0.0f ? x : SLOPE * x;
}

struct alignas(8) h4 { __half2 a, b; };

// ---------- kernel A: edge binning by dst>>9 (packed 4B entries) + W1 transpose tail ----------
__global__ __launch_bounds__(256) void bucket_and_convert(
    const int* __restrict__ ei, const float* __restrict__ W1,
    int* __restrict__ gcnt, int* __restrict__ buf, _Float16* __restrict__ W1T)
{
    if (blockIdx.x >= BKT_BLOCKS) {
        int idx = (blockIdx.x - BKT_BLOCKS) * 256 + threadIdx.x;
        int k = idx >> 8;
        int c = idx & 255;
        W1T[c * IN_D + k] = (_Float16)W1[idx];
        return;
    }

    __shared__ int hist[NBKT], curb[NBKT], gbase[NBKT];
    const int t = threadIdx.x;
    for (int i = t; i < NBKT; i += 256) { hist[i] = 0; curb[i] = 0; }
    __syncthreads();

    const int base = blockIdx.x * 256 * BB;
    int srcs[BB], dsts[BB];
#pragma unroll
    for (int i = 0; i < BB; i++) {
        const int e = base + i * 256 + t;
        int s = -1, d = -1;
        if (e < ETOT) {
            if (e < EE) { s = ei[e]; d = ei[EE + e]; }
            else        { s = d = e - EE; }
        }
        srcs[i] = s; dsts[i] = d;
        if (d >= 0) atomicAdd(&hist[d >> 9], 1);
    }
    __syncthreads();
    for (int i = t; i < NBKT; i += 256)
        if (hist[i] > 0) gbase[i] = atomicAdd(&gcnt[i], hist[i]);
    __syncthreads();
#pragma unroll
    for (int i = 0; i < BB; i++) {
        if (dsts[i] >= 0) {
            int b = dsts[i] >> 9;
            int slot = atomicAdd(&curb[b], 1);
            int pos = gbase[b] + slot;
            // pack: local-dst (9b) << 17 | src (17b; NN < 131072)
            if (pos < BCAP) buf[b * BCAP + pos] = ((dsts[i] & 511) << 17) | srcs[i];
        }
    }
}

// ---------- kernel B: per-bucket CSR placement (parity-split) + MFMA gemm1 (32-node tiles) ----------
__global__ __launch_bounds__(256) void csr_and_gemm(
    const int* __restrict__ gcnt, const int* __restrict__ buf,
    int* __restrict__ deg, int* __restrict__ csr,
    const float* __restrict__ x, const _Float16* __restrict__ W1T,
    const float* __restrict__ a1s, const float* __restrict__ a1d,
    __half* __restrict__ hh1, float* __restrict__ s1s, float* __restrict__ s1d)
{
    __shared__ int cur[256];
    __shared__ _Float16 xl[32][136];

    if (blockIdx.x < CSR_BLOCKS) {
        const int t = threadIdx.x;
        const int b = blockIdx.x >> 1;
        const int par = blockIdx.x & 1;
        cur[t] = 0;
        __syncthreads();
        const int cnt = min(gcnt[b], BCAP);
        const int* bp = buf + b * BCAP;
        const int n0 = b * 512;
        for (int i = t; i < cnt; i += 256) {
            int v = bp[i];
            int dl = v >> 17;
            if ((dl & 1) == par) {
                int slot = atomicAdd(&cur[dl >> 1], 1);
                if (slot < SLOTS) csr[(n0 + dl) * SLOTS + slot] = v & 0x1FFFF;
            }
        }
        __syncthreads();
        const int n = n0 + 2 * t + par;              // node for counter t
        if (n < NN) deg[n] = min(cur[t], SLOTS);
        return;
    }

    // ---- gemm path: h1 = x @ W1 via MFMA, 32 nodes/block, fused s1 scores ----
    const int tid = threadIdx.x;
    const int n0 = (blockIdx.x - CSR_BLOCKS) * 32;
    {
        const int row = tid >> 3;               // 0..31
        const int col = (tid & 7) * 16;         // 0..112 step 16
        const float4* xs = (const float4*)(x + (long)(n0 + row) * IN_D + col);
        float4 v0 = xs[0], v1 = xs[1], v2 = xs[2], v3 = xs[3];
        f16x8 ha, hb2;
        ha[0] = (_Float16)v0.x; ha[1] = (_Float16)v0.y;
        ha[2] = (_Float16)v0.z; ha[3] = (_Float16)v0.w;
        ha[4] = (_Float16)v1.x; ha[5] = (_Float16)v1.y;
        ha[6] = (_Float16)v1.z; ha[7] = (_Float16)v1.w;
        hb2[0] = (_Float16)v2.x; hb2[1] = (_Float16)v2.y;
        hb2[2] = (_Float16)v2.z; hb2[3] = (_Float16)v2.w;
        hb2[4] = (_Float16)v3.x; hb2[5] = (_Float16)v3.y;
        hb2[6] = (_Float16)v3.z; hb2[7] = (_Float16)v3.w;
        *(f16x8*)&xl[row][col] = ha;
        *(f16x8*)&xl[row][col + 8] = hb2;
    }
    __syncthreads();

    const int lane = tid & 63;
    const int w = tid >> 6;                     // wave = head
    const int nd = lane & 15;                   // node within 16-tile
    const int g = lane >> 4;                    // k-group / channel-group

    f16x8 bfrag[2][4];
#pragma unroll
    for (int nt = 0; nt < 2; nt++)
#pragma unroll
        for (int ks = 0; ks < 4; ks++)
            bfrag[nt][ks] = *(const f16x8*)&xl[nt * 16 + nd][ks * 32 + g * 8];

    f32x4 acc[4][2];
#pragma unroll
    for (int t = 0; t < 4; t++)
#pragma unroll
        for (int nt = 0; nt < 2; nt++)
            acc[t][nt] = (f32x4){0.f, 0.f, 0.f, 0.f};

#pragma unroll
    for (int t = 0; t < 4; t++) {
        const _Float16* wbase = W1T + (64 * w + 16 * t + nd) * IN_D + g * 8;
#pragma unroll
        for (int ks = 0; ks < 4; ks++) {
            f16x8 afrag = *(const f16x8*)(wbase + ks * 32);
            acc[t][0] = __builtin_amdgcn_mfma_f32_16x16x32_f16(
                afrag, bfrag[0][ks], acc[t][0], 0, 0, 0);
            acc[t][1] = __builtin_amdgcn_mfma_f32_16x16x32_f16(
                afrag, bfrag[1][ks], acc[t][1], 0, 0, 0);
        }
    }

    float vs[2] = {0.f, 0.f}, vd[2] = {0.f, 0.f};
#pragma unroll
    for (int t = 0; t < 4; t++) {
        const int cbase = 64 * w + 16 * t + 4 * g;
        const float4 as4 = *(const float4*)(a1s + cbase);
        const float4 ad4 = *(const float4*)(a1d + cbase);
#pragma unroll
        for (int nt = 0; nt < 2; nt++) {
            vs[nt] += acc[t][nt][0] * as4.x + acc[t][nt][1] * as4.y
                    + acc[t][nt][2] * as4.z + acc[t][nt][3] * as4.w;
            vd[nt] += acc[t][nt][0] * ad4.x + acc[t][nt][1] * ad4.y
                    + acc[t][nt][2] * ad4.z + acc[t][nt][3] * ad4.w;
            h4 hv;
            hv.a = __floats2half2_rn(acc[t][nt][0], acc[t][nt][1]);
            hv.b = __floats2half2_rn(acc[t][nt][2], acc[t][nt][3]);
            *(h4*)&hh1[(long)(n0 + nt * 16 + nd) * C1 + cbase] = hv;
        }
    }
#pragma unroll
    for (int nt = 0; nt < 2; nt++) {
        float s = vs[nt], d = vd[nt];
        s += __shfl_xor(s, 16); s += __shfl_xor(s, 32);
        d += __shfl_xor(d, 16); d += __shfl_xor(d, 32);
        if (lane < 16) {
            s1s[(n0 + nt * 16 + lane) * NHEAD + w] = s;
            s1d[(n0 + nt * 16 + lane) * NHEAD + w] = d;
        }
    }
}

// ---------- fused layer-1: wave per dst, uniform masked 16-edge chunks ----------
__global__ __launch_bounds__(256) void l1_fused(
    const int* __restrict__ csr, const int* __restrict__ deg,
    const float* __restrict__ s1s, const float* __restrict__ s1d,
    const __half* __restrict__ hh1, const float* __restrict__ b1,
    const float* __restrict__ W2, const float* __restrict__ a2s,
    const float* __restrict__ a2d, float4* __restrict__ nrec)
{
    const int lane = threadIdx.x & 63;
    const int wid = threadIdx.x >> 6;
    const int n = blockIdx.x * 4 + wid;
    if (n >= NN) return;

    const int eid = lane & 15;
    const int h = lane >> 4;
    const int hsel = lane & 48;
    const int dn = deg[n];                      // pre-clamped <= SLOTS, >= 1
    const int st = n * SLOTS;
    const h4* __restrict__ hb = (const h4*)hh1; // h4-unit base (row = 64 h4)

    const float4 sdv = ((const float4*)s1d)[n];
    const float sdh = (h == 0) ? sdv.x : (h == 1) ? sdv.y
                    : (h == 2) ? sdv.z : sdv.w;

    float a0 = 0.f, a1 = 0.f, a2 = 0.f, a3 = 0.f, dl = 0.f;

    const int nch = (dn + 15) >> 4;
    for (int c = 0; c < nch; ++c) {
        const int idx = c * 16 + eid;
        const int eidx = idx < dn ? idx : dn - 1;     // clamp to valid slot
        int sc = csr[st + eidx];
        float ssh = s1s[sc * 4 + h];                  // scalar gather, own head
        float w = (idx < dn) ? __expf(lrelu(ssh + sdh)) : 0.f;
#pragma unroll
        for (int j = 0; j < 16; ++j) {
            int sj = __builtin_amdgcn_readlane(sc, j);
            float wv = __shfl(w, hsel | j);           // 0 for masked edges
            h4 hv = hb[(sj << 6) + lane];             // 32-bit row indexing
            float2 f01 = __half22float2(hv.a);
            float2 f23 = __half22float2(hv.b);
            dl += wv;
            a0 = fmaf(wv, f01.x, a0);
            a1 = fmaf(wv, f01.y, a1);
            a2 = fmaf(wv, f23.x, a2);
            a3 = fmaf(wv, f23.y, a3);
        }
    }

    const float4 bv = ((const float4*)b1)[lane];
    float v0 = a0 / dl + bv.x;
    float v1 = a1 / dl + bv.y;
    float v2 = a2 / dl + bv.z;
    float v3 = a3 / dl + bv.w;
    v0 = v0 > 0.f ? v0 : expm1f(v0);
    v1 = v1 > 0.f ? v1 : expm1f(v1);
    v2 = v2 > 0.f ? v2 : expm1f(v2);
    v3 = v3 > 0.f ? v3 : expm1f(v3);

    const float4 wa = ((const float4*)W2)[lane * 2];
    const float4 wb = ((const float4*)W2)[lane * 2 + 1];
    float p0 = v0 * wa.x + v1 * wa.z + v2 * wb.x + v3 * wb.z;
    float p1 = v0 * wa.y + v1 * wa.w + v2 * wb.y + v3 * wb.w;
#pragma unroll
    for (int off = 32; off >= 1; off >>= 1) {
        p0 += __shfl_xor(p0, off);
        p1 += __shfl_xor(p1, off);
    }
    if (lane == 0) {
        nrec[n] = make_float4(p0, p1,
                              p0 * a2s[0] + p1 * a2s[1],
                              p0 * a2d[0] + p1 * a2d[1]);
    }
}

// ---------- fused layer-2: 16 lanes per dst, single 16B gather per edge ----------
__global__ __launch_bounds__(256) void l2_fused(
    const int* __restrict__ csr, const int* __restrict__ deg,
    const float4* __restrict__ nrec, const float* __restrict__ b2,
    float* __restrict__ out)
{
    const int sl = threadIdx.x & 15;
    const int grp = threadIdx.x >> 4;
    const int n = blockIdx.x * 16 + grp;
    if (n >= NN) return;

    const int dn = deg[n];
    const float sd = nrec[n].w;
    float den = 0.f, a0 = 0.f, a1 = 0.f;
    for (int slot = sl; slot < dn; slot += 16) {
        int s = csr[n * SLOTS + slot];
        float4 r = nrec[s];
        float w = __expf(lrelu(r.z + sd));
        den += w;
        a0 = fmaf(w, r.x, a0);
        a1 = fmaf(w, r.y, a1);
    }
#pragma unroll
    for (int off = 8; off >= 1; off >>= 1) {
        den += __shfl_xor(den, off);
        a0  += __shfl_xor(a0, off);
        a1  += __shfl_xor(a1, off);
    }
    if (sl == 0) {
        out[n * 2]     = a0 / den + b2[0];
        out[n * 2 + 1] = a1 / den + b2[1];
    }
}

extern "C" void kernel_launch(void* const* d_in, const int* in_sizes, int n_in,
                              void* d_out, int out_size, void* d_ws, size_t ws_size,
                              hipStream_t stream) {
    const float* x   = (const float*)d_in[0];
    const int*   ei  = (const int*)d_in[1];
    const float* W1  = (const float*)d_in[2];
    const float* a1s = (const float*)d_in[3];
    const float* a1d = (const float*)d_in[4];
    const float* b1  = (const float*)d_in[5];
    const float* W2  = (const float*)d_in[6];
    const float* a2s = (const float*)d_in[7];
    const float* a2d = (const float*)d_in[8];
    const float* b2  = (const float*)d_in[9];
    float* out = (float*)d_out;

    // workspace layout (all segments 16B-aligned)
    float* ws = (float*)d_ws;
    __half* hh1 = (__half*)ws;                   // NN*C1 halves = 51.2 MB
    float* s1s = ws + (long)NN * C1 / 2;         // NN*4 floats
    float* s1d = s1s + NN * NHEAD;               // NN*4 floats
    float4* nrec = (float4*)(s1d + NN * NHEAD);  // NN float4 = 1.6 MB
    int* deg  = (int*)(nrec + NN);               // NN
    int* csr  = deg + NN;                        // NN*SLOTS = 25.6 MB
    _Float16* W1T = (_Float16*)(csr + (long)NN * SLOTS); // 64 KB
    int* gcnt = (int*)(W1T + C1 * IN_D);         // 256 ints (memset region)
    int* buf = gcnt + 256;                       // NBKT*BCAP ints = 9.6 MB

    hipMemsetAsync(gcnt, 0, 256 * sizeof(int), stream);

    bucket_and_convert<<<BKT_BLOCKS + CONV_BLOCKS, 256, 0, stream>>>(
        ei, W1, gcnt, buf, W1T);
    csr_and_gemm<<<CSR_BLOCKS + GEMM_BLOCKS, 256, 0, stream>>>(
        gcnt, buf, deg, csr, x, W1T, a1s, a1d, hh1, s1s, s1d);
    l1_fused<<<(NN + 3) / 4, 256, 0, stream>>>(csr, deg, s1s, s1d, hh1,
                                               b1, W2, a2s, a2d, nrec);
    l2_fused<<<(NN + 15) / 16, 256, 0, stream>>>(csr, deg, nrec, b2, out);
}